// Round 14
// baseline (780.814 us; speedup 1.0000x reference)
//
#include <hip/hip_runtime.h>

typedef __bf16 bf16_t;
typedef __bf16 bf16x8 __attribute__((ext_vector_type(8)));
typedef float f32x16 __attribute__((ext_vector_type(16)));
typedef float f32x4 __attribute__((ext_vector_type(4)));

#define NB 8
#define NC 256
#define NN 4096

__device__ __forceinline__ f32x16 mfma32(bf16x8 a, bf16x8 b, f32x16 c) {
  return __builtin_amdgcn_mfma_f32_32x32x16_bf16(a, b, c, 0, 0, 0);
}

__device__ __forceinline__ f32x4 mfma16(uint2 a, uint2 b, f32x4 c) {
  union { uint2 u; long long l; } A, B;
  A.u = a; B.u = b;
  return __builtin_amdgcn_mfma_f32_16x16x32_fp8_fp8(A.l, B.l, c, 0, 0, 0);
}

__device__ __forceinline__ void gload_lds16(const void* g, void* l) {
  __builtin_amdgcn_global_load_lds((const __attribute__((address_space(1))) void*)g,
                                   (__attribute__((address_space(3))) void*)l, 16, 0, 0);
}

__device__ __forceinline__ unsigned int packbf2(float lo, float hi) {
  union { bf16_t h; unsigned short s; } a, b;
  a.h = (bf16_t)lo; b.h = (bf16_t)hi;
  return (unsigned int)a.s | ((unsigned int)b.s << 16);
}

__device__ __forceinline__ f32x16 fzero() {
  f32x16 z;
#pragma unroll
  for (int r = 0; r < 16; r++) z[r] = 0.f;
  return z;
}

// post-QK score scale: (1/W) * log2(e)  (softmax in exp2 domain, no shift: P~1)
#define QSCALE (0.015625f * 1.44269504088896f)

// ---------------- Kernel 1: x transpose + (blocks 0..767) weight convert ------
__global__ void ktranspose(const float* __restrict__ x, bf16_t* __restrict__ fT,
                           const float* __restrict__ Wq, const float* __restrict__ bq,
                           const float* __restrict__ Wk, const float* __restrict__ bk,
                           const float* __restrict__ Wv, const float* __restrict__ bv,
                           bf16_t* __restrict__ Wc, float* __restrict__ bc) {
  __shared__ float tile[64][65];
  int bid = blockIdx.x;
  int t = threadIdx.x;
  if (bid < 768) {   // fused weight conversion (768*256 elements)
    int idx = bid * 256 + t;
    int d = idx >> 8;
    float w;
    if (d < 256)      w = Wq[idx];
    else if (d < 512) w = Wk[idx - 65536];
    else              w = Wv[idx - 131072];
    Wc[idx] = (bf16_t)w;
    if (idx < 768) {
      float v = idx < 256 ? bq[idx] : (idx < 512 ? bk[idx - 256] : bv[idx - 512]);
      bc[idx] = v;
    }
  }
  int b = bid >> 8;
  int r = bid & 255;
  int n0 = (r >> 2) * 64;
  int c0 = (r & 3) * 64;
  const float* xb = x + ((long)b * NC + c0) * NN + n0;
  int lr = t >> 4;
  int lc = (t & 15) * 4;
#pragma unroll
  for (int i = 0; i < 4; i++) {
    float4 v4 = *(const float4*)(xb + (long)(lr + i * 16) * NN + lc);
    tile[lr + i * 16][lc + 0] = v4.x; tile[lr + i * 16][lc + 1] = v4.y;
    tile[lr + i * 16][lc + 2] = v4.z; tile[lr + i * 16][lc + 3] = v4.w;
  }
  __syncthreads();
  int nl = t >> 2;
  int cc = (t & 3) * 16;
  bf16_t* dst = fT + ((long)b * NN + n0 + nl) * NC + c0 + cc;
  union { bf16_t h[8]; uint4 u; } p0, p1;
#pragma unroll
  for (int j = 0; j < 8; j++) p0.h[j] = (bf16_t)tile[cc + j][nl];
#pragma unroll
  for (int j = 0; j < 8; j++) p1.h[j] = (bf16_t)tile[cc + 8 + j][nl];
  *(uint4*)dst = p0.u;
  *(uint4*)(dst + 8) = p1.u;
}

// ---------------- Kernel 3: projection GEMM [768,256]x[256,32768] ------------
// XCD-aware: the 6 blocks sharing one fT tile differ by 256 (same XCD -> L2 hit)
// outputs (fp8 e4m3), PAIRED frag-major for 16x16x32 mfma (16B/lane slots):
//   q tiles Kd[b][nt]: byte ((j>>1)*2+h)*1024 + l*16 + (j&1)*8 + e
//       = q[n=16h+(l&15)][c=j*32+((l>>4)&3)*8+e]
//   v tiles vD[b][nt]: byte (ct>>1)*1024 + l*16 + (ct&1)*8 + e
//       = v[c=ct*16+(l&15)][n=16(e>>2)+4((l>>4)&3)+(e&3)]
//   k as [B][N][C]
__global__ __launch_bounds__(256) void kproj(const bf16_t* __restrict__ Wc, const float* __restrict__ bc,
                                             const bf16_t* __restrict__ fT,
                                             unsigned char* __restrict__ qT8, unsigned char* __restrict__ kT8,
                                             unsigned char* __restrict__ vO8) {
  __shared__ bf16_t ft[128 * 256];  // XOR-swizzled rows, 64KB
  int bid = blockIdx.x;
  int mt = bid >> 8;          // 0..5
  int nb = bid & 255;         // 0..255: sharers of one fT tile are +256 apart
  int d0 = mt * 128;
  int gc0 = nb * 128;
  int b = gc0 >> 12;
  int n0 = gc0 & 4095;
  int t = threadIdx.x, lane = t & 63, w = t >> 6;
  int lm = lane & 31, g = lane >> 5;
  const bf16_t* ftb = fT + ((long)b * NN + n0) * NC;
#pragma unroll
  for (int i2 = 0; i2 < 16; i2++) {
    int call = w * 16 + i2;
    int p = call * 1024 + lane * 16;
    int n = p >> 9, cb = p & 511;
    int scb = cb ^ ((n & 7) << 4);
    gload_lds16(ftb + (long)n * NC + (scb >> 1), (char*)ft + call * 1024);
  }
  __syncthreads();

  f32x16 acc00 = fzero(), acc01 = fzero(), acc10 = fzero(), acc11 = fzero();
  int dbase = d0 + (w >> 1) * 64;
  int nbase = (w & 1) * 64;
  const bf16_t* wr = Wc + (long)dbase * NC;
#pragma unroll
  for (int j = 0; j < 16; j++) {
    int cc = j * 16 + g * 8;
    bf16x8 a0 = *(const bf16x8*)(wr + (long)lm * NC + cc);
    bf16x8 a1 = *(const bf16x8*)(wr + (long)(lm + 32) * NC + cc);
    int row0 = nbase + lm;
    bf16x8 b0 = *(const bf16x8*)((char*)ft + row0 * 512 + ((cc * 2) ^ ((row0 & 7) << 4)));
    int row1 = row0 + 32;
    bf16x8 b1 = *(const bf16x8*)((char*)ft + row1 * 512 + ((cc * 2) ^ ((row1 & 7) << 4)));
    acc00 = mfma32(a0, b0, acc00);
    acc01 = mfma32(a0, b1, acc01);
    acc10 = mfma32(a1, b0, acc10);
    acc11 = mfma32(a1, b1, acc11);
  }

  auto epi = [&](f32x16 a, int dt, int nt2) {
    int db = dbase + dt * 32;
    int colg = n0 + nbase + nt2 * 32 + lm;
    long tb = ((long)b * 128 + (colg >> 5)) * 8192;
    int n5 = colg & 31;
    if (mt >= 4) {        // v rows -> paired frag-major fp8 vD (byte stores)
      int q5 = (n5 >> 2) & 3;
      int e5 = ((n5 >> 4) << 2) + (n5 & 3);
      int ct0 = (db - 512) >> 4;
#pragma unroll
      for (int r = 0; r < 16; r++) {
        int d = db + (r & 3) + 8 * (r >> 2) + 4 * g;
        int ct = ct0 + (r >> 3);
        int kq = (r & 3) + 8 * ((r >> 2) & 1) + 4 * g;
        unsigned int f8 = __builtin_amdgcn_cvt_pk_fp8_f32(a[r] + bc[d], 0.f, 0, false);
        vO8[tb + (ct >> 1) * 1024 + (q5 * 16 + kq) * 16 + (ct & 1) * 8 + e5] = (unsigned char)f8;
      }
    } else if (mt < 2) {  // q rows -> paired frag-major fp8 Kd (u32 stores)
      int h = (n5 >> 4) & 1;
      int nr = n5 & 15;
      int j = db >> 5;
      long ob = tb + ((j >> 1) * 2 + h) * 1024 + (j & 1) * 8;
#pragma unroll
      for (int t4 = 0; t4 < 4; t4++) {
        int cb = db + 8 * t4 + 4 * g;
        unsigned int pk = __builtin_amdgcn_cvt_pk_fp8_f32(a[4 * t4 + 0] + bc[cb + 0],
                                                          a[4 * t4 + 1] + bc[cb + 1], 0, false);
        pk = __builtin_amdgcn_cvt_pk_fp8_f32(a[4 * t4 + 2] + bc[cb + 2],
                                             a[4 * t4 + 3] + bc[cb + 3], pk, true);
        *(unsigned int*)(qT8 + ob + (t4 * 16 + nr) * 16 + 4 * g) = pk;
      }
    } else {              // k rows -> [B][N][C] fp8 (pair ushort stores)
      unsigned char* dst = kT8 + ((long)b * NN + colg) * 256 - 256;
#pragma unroll
      for (int r2 = 0; r2 < 8; r2++) {
        int r = r2 * 2;
        int d = db + (r & 3) + 8 * (r >> 2) + 4 * g;
        unsigned int pk = __builtin_amdgcn_cvt_pk_fp8_f32(a[r] + bc[d], a[r + 1] + bc[d + 1], 0, false);
        *(unsigned short*)(dst + d) = (unsigned short)pk;
      }
    }
  };
  epi(acc00, 0, 0); epi(acc01, 0, 1); epi(acc10, 1, 0); epi(acc11, 1, 1);
}

// ---------------- Kernel 4: fp8 flash attention, 16x16 frags, 8 waves --------
// R13 structure unchanged; nsplit=4 -> 4 blocks/CU (8 waves/SIMD, VGPR<=64).
__global__ __launch_bounds__(512, 8) void kattn(const unsigned char* __restrict__ qT8,
                                                const unsigned char* __restrict__ kT8,
                                                const unsigned char* __restrict__ vO8,
                                                char* __restrict__ RR0, char* __restrict__ RR1,
                                                char* __restrict__ RR2, char* __restrict__ RR3,
                                                int iters) {
  __shared__ unsigned char Kt[2][8192];   // paired frag-major fp8
  __shared__ unsigned char Vt[2][8192];
  int bid = blockIdx.x;
  int b = bid & 7;
  int mtile = (bid >> 3) & 31;
  int split = bid >> 8;
  int nt0 = split * iters, ntE = nt0 + iters;
  int t = threadIdx.x, lane = t & 63, w = t >> 6;   // 8 waves
  int l4 = lane & 15, q = (lane >> 4) & 3;
  int mw = mtile * 128 + w * 16;
  const unsigned char* qb = qT8 + (long)b * 1048576;    // 128 tiles x 8192 B
  const unsigned char* vtb = vO8 + (long)b * 1048576;

  // B-frags of the flash-query (k-projection), col m = l4, k = q*8+e
  uint2 qf[8];
  const unsigned char* kb = kT8 + ((long)b * NN + mw + l4) * 256 + q * 8;
#pragma unroll
  for (int j = 0; j < 8; j++) qf[j] = *(const uint2*)(kb + j * 32);

  f32x4 acc[16];
#pragma unroll
  for (int ct = 0; ct < 16; ct++) acc[ct] = f32x4{0.f, 0.f, 0.f, 0.f};
  float lsum = 0.f;

  auto stageK = [&](int nt, int bufi) {
    gload_lds16(qb + (long)nt * 8192 + w * 1024 + lane * 16, &Kt[bufi][w * 1024]);
  };
  auto stageV = [&](int nt, int bufi) {
    gload_lds16(vtb + (long)nt * 8192 + w * 1024 + lane * 16, &Vt[bufi][w * 1024]);
  };

  stageK(nt0, 0);
  stageV(nt0, 0);
  __syncthreads();

  int buf = 0;
  for (int nt = nt0; nt < ntE; nt++) {
    bool more = nt + 1 < ntE;
    if (more) { stageK(nt + 1, buf ^ 1); stageV(nt + 1, buf ^ 1); }
    // ---- QK^T (swapped): paired b128 frag reads, 4 mfma per j2 ----
    __builtin_amdgcn_s_setprio(1);
    const unsigned char* kbase = &Kt[buf][0] + lane * 16;
    f32x4 s0 = f32x4{0.f, 0.f, 0.f, 0.f}, s1 = f32x4{0.f, 0.f, 0.f, 0.f};
#pragma unroll
    for (int j2 = 0; j2 < 4; j2++) {
      uint4 h0 = *(const uint4*)(kbase + (j2 * 2) * 1024);
      s0 = mfma16(make_uint2(h0.x, h0.y), qf[2 * j2], s0);
      s0 = mfma16(make_uint2(h0.z, h0.w), qf[2 * j2 + 1], s0);
      uint4 h1 = *(const uint4*)(kbase + (j2 * 2 + 1) * 1024);
      s1 = mfma16(make_uint2(h1.x, h1.y), qf[2 * j2], s1);
      s1 = mfma16(make_uint2(h1.z, h1.w), qf[2 * j2 + 1], s1);
    }
    __builtin_amdgcn_s_setprio(0);
    // ---- softmax (exp2 domain, no shift); lane holds 8 of 32 n's ----
    float e[8];
#pragma unroll
    for (int r = 0; r < 4; r++) {
      e[r] = __builtin_amdgcn_exp2f(s0[r] * QSCALE);
      e[4 + r] = __builtin_amdgcn_exp2f(s1[r] * QSCALE);
    }
    lsum += ((e[0] + e[1]) + (e[2] + e[3])) + ((e[4] + e[5]) + (e[6] + e[7]));
    uint2 pf;
    pf.x = __builtin_amdgcn_cvt_pk_fp8_f32(e[0], e[1], 0, false);
    pf.x = __builtin_amdgcn_cvt_pk_fp8_f32(e[2], e[3], pf.x, true);
    pf.y = __builtin_amdgcn_cvt_pk_fp8_f32(e[4], e[5], 0, false);
    pf.y = __builtin_amdgcn_cvt_pk_fp8_f32(e[6], e[7], pf.y, true);
    // ---- PV: paired b128 frag reads, 2 mfma per ct2 ----
    __builtin_amdgcn_s_setprio(1);
    const unsigned char* vbase = &Vt[buf][0] + lane * 16;
#pragma unroll
    for (int ct2 = 0; ct2 < 8; ct2++) {
      uint4 vv = *(const uint4*)(vbase + ct2 * 1024);
      acc[2 * ct2] = mfma16(make_uint2(vv.x, vv.y), pf, acc[2 * ct2]);
      acc[2 * ct2 + 1] = mfma16(make_uint2(vv.z, vv.w), pf, acc[2 * ct2 + 1]);
    }
    __builtin_amdgcn_s_setprio(0);
    __syncthreads();
    buf ^= 1;
  }
  // ---- epilogue: reduce lsum over q-groups; write bf16 partials ----
  float ltot = lsum + __shfl_xor(lsum, 16, 64);
  ltot += __shfl_xor(ltot, 32, 64);
  char* R = split == 0 ? RR0 : (split == 1 ? RR1 : (split == 2 ? RR2 : RR3));
  unsigned int* PP = (unsigned int*)R;
  float* MLf = (float*)(R + 16777216);
  int mg = ((b * 32 + mtile) << 3) + w;
  if (lane < 16) MLf[mg * 16 + lane] = ltot;
#pragma unroll
  for (int ct = 0; ct < 16; ct++) {
    uint2 pk;
    pk.x = packbf2(acc[ct][0], acc[ct][1]);
    pk.y = packbf2(acc[ct][2], acc[ct][3]);
    *(uint2*)(PP + (mg * 16 + ct) * 128 + lane * 2) = pk;
  }
}

// ---------------- Kernel 5: combine splits, normalize, gamma*o + x -----------
__global__ __launch_bounds__(256) void kcombine(const char* __restrict__ RR0, const char* __restrict__ RR1,
                                                const char* __restrict__ RR2, const char* __restrict__ RR3,
                                                int nsplit, const float* __restrict__ x,
                                                const float* __restrict__ gma, float* __restrict__ out) {
  int tid = blockIdx.x * 256 + threadIdx.x;   // 4.19M threads, 2 outputs each
  int mg = tid >> 11;
  int ct = (tid >> 7) & 15;
  int lane = (tid >> 1) & 63;
  int rr = tid & 1;
  int b = mg >> 8, mtile = (mg >> 3) & 31, w = mg & 7;
  int m = mtile * 128 + w * 16 + (lane & 15);
  int c0 = ct * 16 + ((lane >> 4) & 3) * 4 + rr * 2;
  float ox = 0.f, oy = 0.f, L = 0.f;
  const char* Rs[4] = {RR0, RR1, RR2, RR3};
#pragma unroll 1
  for (int s = 0; s < nsplit; s++) {    // no shift: splits combine by addition
    unsigned int p = ((const unsigned int*)Rs[s])[tid];
    ox += __uint_as_float(p << 16);
    oy += __uint_as_float(p & 0xffff0000u);
    L += ((const float*)(Rs[s] + 16777216))[mg * 16 + (lane & 15)];
  }
  float sc = gma[0] / L;
  long o0 = ((long)(b * NC + c0)) * NN + m;
  out[o0] = ox * sc + x[o0];
  out[o0 + NN] = oy * sc + x[o0 + NN];
}

extern "C" void kernel_launch(void* const* d_in, const int* in_sizes, int n_in,
                              void* d_out, int out_size, void* d_ws, size_t ws_size,
                              hipStream_t stream) {
  const float* x   = (const float*)d_in[0];
  const float* Wq  = (const float*)d_in[1];
  const float* bq  = (const float*)d_in[2];
  const float* Wk  = (const float*)d_in[3];
  const float* bk  = (const float*)d_in[4];
  const float* Wv  = (const float*)d_in[5];
  const float* bv  = (const float*)d_in[6];
  const float* gma = (const float*)d_in[7];
  float* out = (float*)d_out;
  char* ws = (char*)d_ws;
  // layout (bytes): qT8 8.39M | kT8 8.39M | vO8 8.39M | fT 16.78M | Wc | bc | R1..R3
  unsigned char* qT8 = (unsigned char*)(ws);
  unsigned char* kT8 = (unsigned char*)(ws + 8388608);
  unsigned char* vO8 = (unsigned char*)(ws + 16777216);
  bf16_t* fT = (bf16_t*)(ws + 25165824);
  bf16_t* Wc = (bf16_t*)(ws + 41943040);
  float*  bc = (float*)(ws + 42336256);
  const size_t RSZ = 16908288;
  char* R0 = ws + 25165824;         // reuses fT + Wc/bc (dead after kproj)
  char* R1 = ws + 42340352;
  char* R2 = R1 + RSZ;
  char* R3 = R2 + RSZ;
  size_t need2 = 42340352 + RSZ;
  size_t need4 = 42340352 + 3 * RSZ;
  int nsplit = (ws_size >= need4) ? 4 : ((ws_size >= need2) ? 2 : 1);

  ktranspose<<<2048, 256, 0, stream>>>(x, fT, Wq, bq, Wk, bk, Wv, bv, Wc, bc);
  kproj<<<1536, 256, 0, stream>>>(Wc, bc, fT, qT8, kT8, vO8);
  kattn<<<256 * nsplit, 512, 0, stream>>>(qT8, kT8, vO8, R0, R1, R2, R3, 128 / nsplit);
  kcombine<<<16384, 256, 0, stream>>>(R0, R1, R2, R3, nsplit, x, gma, out);
}

// Round 15
// 165.809 us; speedup vs baseline: 4.7091x; 4.7091x over previous
//
#include <hip/hip_runtime.h>

typedef __bf16 bf16_t;
typedef __bf16 bf16x8 __attribute__((ext_vector_type(8)));
typedef float f32x16 __attribute__((ext_vector_type(16)));
typedef float f32x4 __attribute__((ext_vector_type(4)));

#define NB 8
#define NC 256
#define NN 4096

__device__ __forceinline__ f32x16 mfma32(bf16x8 a, bf16x8 b, f32x16 c) {
  return __builtin_amdgcn_mfma_f32_32x32x16_bf16(a, b, c, 0, 0, 0);
}

__device__ __forceinline__ f32x4 mfma16(uint2 a, uint2 b, f32x4 c) {
  union { uint2 u; long long l; } A, B;
  A.u = a; B.u = b;
  return __builtin_amdgcn_mfma_f32_16x16x32_fp8_fp8(A.l, B.l, c, 0, 0, 0);
}

__device__ __forceinline__ void gload_lds16(const void* g, void* l) {
  __builtin_amdgcn_global_load_lds((const __attribute__((address_space(1))) void*)g,
                                   (__attribute__((address_space(3))) void*)l, 16, 0, 0);
}

__device__ __forceinline__ unsigned int packbf2(float lo, float hi) {
  union { bf16_t h; unsigned short s; } a, b;
  a.h = (bf16_t)lo; b.h = (bf16_t)hi;
  return (unsigned int)a.s | ((unsigned int)b.s << 16);
}

__device__ __forceinline__ f32x16 fzero() {
  f32x16 z;
#pragma unroll
  for (int r = 0; r < 16; r++) z[r] = 0.f;
  return z;
}

// post-QK score scale: (1/W) * log2(e)  (softmax in exp2 domain, no shift: P~1)
#define QSCALE (0.015625f * 1.44269504088896f)

// ---------------- Kernel 1: x transpose + (blocks 0..767) weight convert ------
__global__ void ktranspose(const float* __restrict__ x, bf16_t* __restrict__ fT,
                           const float* __restrict__ Wq, const float* __restrict__ bq,
                           const float* __restrict__ Wk, const float* __restrict__ bk,
                           const float* __restrict__ Wv, const float* __restrict__ bv,
                           bf16_t* __restrict__ Wc, float* __restrict__ bc) {
  __shared__ float tile[64][65];
  int bid = blockIdx.x;
  int t = threadIdx.x;
  if (bid < 768) {   // fused weight conversion (768*256 elements)
    int idx = bid * 256 + t;
    int d = idx >> 8;
    float w;
    if (d < 256)      w = Wq[idx];
    else if (d < 512) w = Wk[idx - 65536];
    else              w = Wv[idx - 131072];
    Wc[idx] = (bf16_t)w;
    if (idx < 768) {
      float v = idx < 256 ? bq[idx] : (idx < 512 ? bk[idx - 256] : bv[idx - 512]);
      bc[idx] = v;
    }
  }
  int b = bid >> 8;
  int r = bid & 255;
  int n0 = (r >> 2) * 64;
  int c0 = (r & 3) * 64;
  const float* xb = x + ((long)b * NC + c0) * NN + n0;
  int lr = t >> 4;
  int lc = (t & 15) * 4;
#pragma unroll
  for (int i = 0; i < 4; i++) {
    float4 v4 = *(const float4*)(xb + (long)(lr + i * 16) * NN + lc);
    tile[lr + i * 16][lc + 0] = v4.x; tile[lr + i * 16][lc + 1] = v4.y;
    tile[lr + i * 16][lc + 2] = v4.z; tile[lr + i * 16][lc + 3] = v4.w;
  }
  __syncthreads();
  int nl = t >> 2;
  int cc = (t & 3) * 16;
  bf16_t* dst = fT + ((long)b * NN + n0 + nl) * NC + c0 + cc;
  union { bf16_t h[8]; uint4 u; } p0, p1;
#pragma unroll
  for (int j = 0; j < 8; j++) p0.h[j] = (bf16_t)tile[cc + j][nl];
#pragma unroll
  for (int j = 0; j < 8; j++) p1.h[j] = (bf16_t)tile[cc + 8 + j][nl];
  *(uint4*)dst = p0.u;
  *(uint4*)(dst + 8) = p1.u;
}

// ---------------- Kernel 2: projection GEMM [768,256]x[256,32768] ------------
// XCD-aware: the 6 blocks sharing one fT tile differ by 256 (same XCD -> L2 hit)
// outputs (fp8 e4m3), PAIRED frag-major for 16x16x32 mfma (16B/lane slots):
//   q tiles Kd[b][nt]: byte ((j>>1)*2+h)*1024 + l*16 + (j&1)*8 + e
//       = q[n=16h+(l&15)][c=j*32+((l>>4)&3)*8+e]
//   v tiles vD[b][nt]: byte (ct>>1)*1024 + l*16 + (ct&1)*8 + e
//       = v[c=ct*16+(l&15)][n=16(e>>2)+4((l>>4)&3)+(e&3)]
//   k as [B][N][C]
__global__ __launch_bounds__(256) void kproj(const bf16_t* __restrict__ Wc, const float* __restrict__ bc,
                                             const bf16_t* __restrict__ fT,
                                             unsigned char* __restrict__ qT8, unsigned char* __restrict__ kT8,
                                             unsigned char* __restrict__ vO8) {
  __shared__ bf16_t ft[128 * 256];  // XOR-swizzled rows, 64KB
  int bid = blockIdx.x;
  int mt = bid >> 8;          // 0..5
  int nb = bid & 255;         // 0..255: sharers of one fT tile are +256 apart
  int d0 = mt * 128;
  int gc0 = nb * 128;
  int b = gc0 >> 12;
  int n0 = gc0 & 4095;
  int t = threadIdx.x, lane = t & 63, w = t >> 6;
  int lm = lane & 31, g = lane >> 5;
  const bf16_t* ftb = fT + ((long)b * NN + n0) * NC;
#pragma unroll
  for (int i2 = 0; i2 < 16; i2++) {
    int call = w * 16 + i2;
    int p = call * 1024 + lane * 16;
    int n = p >> 9, cb = p & 511;
    int scb = cb ^ ((n & 7) << 4);
    gload_lds16(ftb + (long)n * NC + (scb >> 1), (char*)ft + call * 1024);
  }
  __syncthreads();

  f32x16 acc00 = fzero(), acc01 = fzero(), acc10 = fzero(), acc11 = fzero();
  int dbase = d0 + (w >> 1) * 64;
  int nbase = (w & 1) * 64;
  const bf16_t* wr = Wc + (long)dbase * NC;
#pragma unroll
  for (int j = 0; j < 16; j++) {
    int cc = j * 16 + g * 8;
    bf16x8 a0 = *(const bf16x8*)(wr + (long)lm * NC + cc);
    bf16x8 a1 = *(const bf16x8*)(wr + (long)(lm + 32) * NC + cc);
    int row0 = nbase + lm;
    bf16x8 b0 = *(const bf16x8*)((char*)ft + row0 * 512 + ((cc * 2) ^ ((row0 & 7) << 4)));
    int row1 = row0 + 32;
    bf16x8 b1 = *(const bf16x8*)((char*)ft + row1 * 512 + ((cc * 2) ^ ((row1 & 7) << 4)));
    acc00 = mfma32(a0, b0, acc00);
    acc01 = mfma32(a0, b1, acc01);
    acc10 = mfma32(a1, b0, acc10);
    acc11 = mfma32(a1, b1, acc11);
  }

  auto epi = [&](f32x16 a, int dt, int nt2) {
    int db = dbase + dt * 32;
    int colg = n0 + nbase + nt2 * 32 + lm;
    long tb = ((long)b * 128 + (colg >> 5)) * 8192;
    int n5 = colg & 31;
    if (mt >= 4) {        // v rows -> paired frag-major fp8 vD (byte stores)
      int q5 = (n5 >> 2) & 3;
      int e5 = ((n5 >> 4) << 2) + (n5 & 3);
      int ct0 = (db - 512) >> 4;
#pragma unroll
      for (int r = 0; r < 16; r++) {
        int d = db + (r & 3) + 8 * (r >> 2) + 4 * g;
        int ct = ct0 + (r >> 3);
        int kq = (r & 3) + 8 * ((r >> 2) & 1) + 4 * g;
        unsigned int f8 = __builtin_amdgcn_cvt_pk_fp8_f32(a[r] + bc[d], 0.f, 0, false);
        vO8[tb + (ct >> 1) * 1024 + (q5 * 16 + kq) * 16 + (ct & 1) * 8 + e5] = (unsigned char)f8;
      }
    } else if (mt < 2) {  // q rows -> paired frag-major fp8 Kd (u32 stores)
      int h = (n5 >> 4) & 1;
      int nr = n5 & 15;
      int j = db >> 5;
      long ob = tb + ((j >> 1) * 2 + h) * 1024 + (j & 1) * 8;
#pragma unroll
      for (int t4 = 0; t4 < 4; t4++) {
        int cb = db + 8 * t4 + 4 * g;
        unsigned int pk = __builtin_amdgcn_cvt_pk_fp8_f32(a[4 * t4 + 0] + bc[cb + 0],
                                                          a[4 * t4 + 1] + bc[cb + 1], 0, false);
        pk = __builtin_amdgcn_cvt_pk_fp8_f32(a[4 * t4 + 2] + bc[cb + 2],
                                             a[4 * t4 + 3] + bc[cb + 3], pk, true);
        *(unsigned int*)(qT8 + ob + (t4 * 16 + nr) * 16 + 4 * g) = pk;
      }
    } else {              // k rows -> [B][N][C] fp8 (pair ushort stores)
      unsigned char* dst = kT8 + ((long)b * NN + colg) * 256 - 256;
#pragma unroll
      for (int r2 = 0; r2 < 8; r2++) {
        int r = r2 * 2;
        int d = db + (r & 3) + 8 * (r >> 2) + 4 * g;
        unsigned int pk = __builtin_amdgcn_cvt_pk_fp8_f32(a[r] + bc[d], a[r + 1] + bc[d + 1], 0, false);
        *(unsigned short*)(dst + d) = (unsigned short)pk;
      }
    }
  };
  epi(acc00, 0, 0); epi(acc01, 0, 1); epi(acc10, 1, 0); epi(acc11, 1, 1);
}

// ---------------- Kernel 3: fp8 flash attention, 16x16 frags, 8 waves --------
// Exact R13 structure (dbuf, one barrier/iter, nsplit=2, 4 waves/SIMD).
// Partials now written as [b][c/2][m] uint (bf16 c-pair) for coalesced combine.
__global__ __launch_bounds__(512, 4) void kattn(const unsigned char* __restrict__ qT8,
                                                const unsigned char* __restrict__ kT8,
                                                const unsigned char* __restrict__ vO8,
                                                char* __restrict__ R0, char* __restrict__ R1, int iters) {
  __shared__ unsigned char Kt[2][8192];   // paired frag-major fp8
  __shared__ unsigned char Vt[2][8192];
  int bid = blockIdx.x;
  int b = bid & 7;
  int mtile = (bid >> 3) & 31;
  int split = bid >> 8;
  int nt0 = split * iters, ntE = nt0 + iters;
  int t = threadIdx.x, lane = t & 63, w = t >> 6;   // 8 waves
  int l4 = lane & 15, q = (lane >> 4) & 3;
  int mw = mtile * 128 + w * 16;
  const unsigned char* qb = qT8 + (long)b * 1048576;    // 128 tiles x 8192 B
  const unsigned char* vtb = vO8 + (long)b * 1048576;

  // B-frags of the flash-query (k-projection), col m = l4, k = q*8+e
  uint2 qf[8];
  const unsigned char* kb = kT8 + ((long)b * NN + mw + l4) * 256 + q * 8;
#pragma unroll
  for (int j = 0; j < 8; j++) qf[j] = *(const uint2*)(kb + j * 32);

  f32x4 acc[16];
#pragma unroll
  for (int ct = 0; ct < 16; ct++) acc[ct] = f32x4{0.f, 0.f, 0.f, 0.f};
  float lsum = 0.f;

  auto stageK = [&](int nt, int bufi) {
    gload_lds16(qb + (long)nt * 8192 + w * 1024 + lane * 16, &Kt[bufi][w * 1024]);
  };
  auto stageV = [&](int nt, int bufi) {
    gload_lds16(vtb + (long)nt * 8192 + w * 1024 + lane * 16, &Vt[bufi][w * 1024]);
  };

  stageK(nt0, 0);
  stageV(nt0, 0);
  __syncthreads();

  int buf = 0;
  for (int nt = nt0; nt < ntE; nt++) {
    bool more = nt + 1 < ntE;
    if (more) { stageK(nt + 1, buf ^ 1); stageV(nt + 1, buf ^ 1); }
    // ---- QK^T (swapped): paired b128 frag reads, 4 mfma per j2 ----
    __builtin_amdgcn_s_setprio(1);
    const unsigned char* kbase = &Kt[buf][0] + lane * 16;
    f32x4 s0 = f32x4{0.f, 0.f, 0.f, 0.f}, s1 = f32x4{0.f, 0.f, 0.f, 0.f};
#pragma unroll
    for (int j2 = 0; j2 < 4; j2++) {
      uint4 h0 = *(const uint4*)(kbase + (j2 * 2) * 1024);
      s0 = mfma16(make_uint2(h0.x, h0.y), qf[2 * j2], s0);
      s0 = mfma16(make_uint2(h0.z, h0.w), qf[2 * j2 + 1], s0);
      uint4 h1 = *(const uint4*)(kbase + (j2 * 2 + 1) * 1024);
      s1 = mfma16(make_uint2(h1.x, h1.y), qf[2 * j2], s1);
      s1 = mfma16(make_uint2(h1.z, h1.w), qf[2 * j2 + 1], s1);
    }
    __builtin_amdgcn_s_setprio(0);
    // ---- softmax (exp2 domain, no shift); lane holds 8 of 32 n's ----
    float e[8];
#pragma unroll
    for (int r = 0; r < 4; r++) {
      e[r] = __builtin_amdgcn_exp2f(s0[r] * QSCALE);
      e[4 + r] = __builtin_amdgcn_exp2f(s1[r] * QSCALE);
    }
    lsum += ((e[0] + e[1]) + (e[2] + e[3])) + ((e[4] + e[5]) + (e[6] + e[7]));
    uint2 pf;
    pf.x = __builtin_amdgcn_cvt_pk_fp8_f32(e[0], e[1], 0, false);
    pf.x = __builtin_amdgcn_cvt_pk_fp8_f32(e[2], e[3], pf.x, true);
    pf.y = __builtin_amdgcn_cvt_pk_fp8_f32(e[4], e[5], 0, false);
    pf.y = __builtin_amdgcn_cvt_pk_fp8_f32(e[6], e[7], pf.y, true);
    // ---- PV: paired b128 frag reads, 2 mfma per ct2 ----
    __builtin_amdgcn_s_setprio(1);
    const unsigned char* vbase = &Vt[buf][0] + lane * 16;
#pragma unroll
    for (int ct2 = 0; ct2 < 8; ct2++) {
      uint4 vv = *(const uint4*)(vbase + ct2 * 1024);
      acc[2 * ct2] = mfma16(make_uint2(vv.x, vv.y), pf, acc[2 * ct2]);
      acc[2 * ct2 + 1] = mfma16(make_uint2(vv.z, vv.w), pf, acc[2 * ct2 + 1]);
    }
    __builtin_amdgcn_s_setprio(0);
    __syncthreads();
    buf ^= 1;
  }
  // ---- epilogue: partials as [b][c/2][m] uint; L as [b][m] f32 ----
  float ltot = lsum + __shfl_xor(lsum, 16, 64);
  ltot += __shfl_xor(ltot, 32, 64);
  char* R = split ? R1 : R0;
  unsigned int* PP = (unsigned int*)R;
  float* MLf = (float*)(R + 16777216);
  if (lane < 16) MLf[b * 4096 + mw + lane] = ltot;
  long base = ((long)b * 128) * 4096 + mw + l4;
#pragma unroll
  for (int ct = 0; ct < 16; ct++) {
    int cp0 = ct * 8 + q * 2;   // c = ct*16 + q*4 + r ; pair (r=0,1) and (r=2,3)
    PP[base + (long)cp0 * 4096] = packbf2(acc[ct][0], acc[ct][1]);
    PP[base + (long)(cp0 + 1) * 4096] = packbf2(acc[ct][2], acc[ct][3]);
  }
}

// ---------------- Kernel 4: combine splits, normalize, gamma*o + x -----------
// tid == partial index [b][cp][m] -> all reads and writes fully coalesced.
__global__ __launch_bounds__(256) void kcombine(const char* __restrict__ R0, const char* __restrict__ R1,
                                                int nsplit, const float* __restrict__ x,
                                                const float* __restrict__ gma, float* __restrict__ out) {
  int tid = blockIdx.x * 256 + threadIdx.x;   // 4.19M threads, 2 outputs each
  int b = tid >> 19;
  int cp = (tid >> 12) & 127;
  int m = tid & 4095;
  unsigned int p0 = ((const unsigned int*)R0)[tid];
  float ox = __uint_as_float(p0 << 16);
  float oy = __uint_as_float(p0 & 0xffff0000u);
  float L = ((const float*)(R0 + 16777216))[b * 4096 + m];
  if (nsplit == 2) {      // no shift: splits combine by plain addition
    unsigned int p1 = ((const unsigned int*)R1)[tid];
    ox += __uint_as_float(p1 << 16);
    oy += __uint_as_float(p1 & 0xffff0000u);
    L += ((const float*)(R1 + 16777216))[b * 4096 + m];
  }
  float sc = gma[0] / L;
  long o0 = ((long)(b * NC + 2 * cp)) * NN + m;
  out[o0] = ox * sc + x[o0];
  out[o0 + NN] = oy * sc + x[o0 + NN];
}

extern "C" void kernel_launch(void* const* d_in, const int* in_sizes, int n_in,
                              void* d_out, int out_size, void* d_ws, size_t ws_size,
                              hipStream_t stream) {
  const float* x   = (const float*)d_in[0];
  const float* Wq  = (const float*)d_in[1];
  const float* bq  = (const float*)d_in[2];
  const float* Wk  = (const float*)d_in[3];
  const float* bk  = (const float*)d_in[4];
  const float* Wv  = (const float*)d_in[5];
  const float* bv  = (const float*)d_in[6];
  const float* gma = (const float*)d_in[7];
  float* out = (float*)d_out;
  char* ws = (char*)d_ws;
  // layout (bytes): qT8 8.39M | kT8 8.39M | vO8 8.39M | fT 16.78M | Wc | bc | R1
  unsigned char* qT8 = (unsigned char*)(ws);
  unsigned char* kT8 = (unsigned char*)(ws + 8388608);
  unsigned char* vO8 = (unsigned char*)(ws + 16777216);
  bf16_t* fT = (bf16_t*)(ws + 25165824);
  bf16_t* Wc = (bf16_t*)(ws + 41943040);
  float*  bc = (float*)(ws + 42336256);
  const size_t RSZ = 16908288;   // 16.78M partials + 131KB L
  char* R0 = ws + 25165824;      // reuses fT + Wc/bc (dead after kproj)
  char* R1 = ws + 42340352;
  size_t need2 = 42340352 + RSZ;
  int nsplit = (ws_size >= need2) ? 2 : 1;

  ktranspose<<<2048, 256, 0, stream>>>(x, fT, Wq, bq, Wk, bk, Wv, bv, Wc, bc);
  kproj<<<1536, 256, 0, stream>>>(Wc, bc, fT, qT8, kT8, vO8);
  kattn<<<256 * nsplit, 512, 0, stream>>>(qT8, kT8, vO8, R0, R1, 128 / nsplit);
  kcombine<<<16384, 256, 0, stream>>>(R0, R1, nsplit, x, gma, out);
}

// Round 17
// 163.081 us; speedup vs baseline: 4.7879x; 1.0167x over previous
//
#include <hip/hip_runtime.h>

typedef __bf16 bf16_t;
typedef __bf16 bf16x8 __attribute__((ext_vector_type(8)));
typedef float f32x16 __attribute__((ext_vector_type(16)));
typedef float f32x4 __attribute__((ext_vector_type(4)));
typedef float f32x2 __attribute__((ext_vector_type(2)));

#define NB 8
#define NC 256
#define NN 4096

__device__ __forceinline__ f32x16 mfma32(bf16x8 a, bf16x8 b, f32x16 c) {
  return __builtin_amdgcn_mfma_f32_32x32x16_bf16(a, b, c, 0, 0, 0);
}

__device__ __forceinline__ f32x4 mfma16(uint2 a, uint2 b, f32x4 c) {
  union { uint2 u; long long l; } A, B;
  A.u = a; B.u = b;
  return __builtin_amdgcn_mfma_f32_16x16x32_fp8_fp8(A.l, B.l, c, 0, 0, 0);
}

__device__ __forceinline__ void gload_lds16(const void* g, void* l) {
  __builtin_amdgcn_global_load_lds((const __attribute__((address_space(1))) void*)g,
                                   (__attribute__((address_space(3))) void*)l, 16, 0, 0);
}

__device__ __forceinline__ unsigned int packbf2(float lo, float hi) {
  union { bf16_t h; unsigned short s; } a, b;
  a.h = (bf16_t)lo; b.h = (bf16_t)hi;
  return (unsigned int)a.s | ((unsigned int)b.s << 16);
}

__device__ __forceinline__ f32x16 fzero() {
  f32x16 z;
#pragma unroll
  for (int r = 0; r < 16; r++) z[r] = 0.f;
  return z;
}

// post-QK score scale: (1/W) * log2(e)  (softmax in exp2 domain, no shift: P~1)
#define QSCALE (0.015625f * 1.44269504088896f)

// ---------------- Kernel 1: x transpose + (blocks 0..767) weight convert ------
__global__ void ktranspose(const float* __restrict__ x, bf16_t* __restrict__ fT,
                           const float* __restrict__ Wq, const float* __restrict__ bq,
                           const float* __restrict__ Wk, const float* __restrict__ bk,
                           const float* __restrict__ Wv, const float* __restrict__ bv,
                           bf16_t* __restrict__ Wc, float* __restrict__ bc) {
  __shared__ float tile[64][65];
  int bid = blockIdx.x;
  int t = threadIdx.x;
  if (bid < 768) {   // fused weight conversion (768*256 elements)
    int idx = bid * 256 + t;
    int d = idx >> 8;
    float w;
    if (d < 256)      w = Wq[idx];
    else if (d < 512) w = Wk[idx - 65536];
    else              w = Wv[idx - 131072];
    Wc[idx] = (bf16_t)w;
    if (idx < 768) {
      float v = idx < 256 ? bq[idx] : (idx < 512 ? bk[idx - 256] : bv[idx - 512]);
      bc[idx] = v;
    }
  }
  int b = bid >> 8;
  int r = bid & 255;
  int n0 = (r >> 2) * 64;
  int c0 = (r & 3) * 64;
  const float* xb = x + ((long)b * NC + c0) * NN + n0;
  int lr = t >> 4;
  int lc = (t & 15) * 4;
#pragma unroll
  for (int i = 0; i < 4; i++) {
    float4 v4 = *(const float4*)(xb + (long)(lr + i * 16) * NN + lc);
    tile[lr + i * 16][lc + 0] = v4.x; tile[lr + i * 16][lc + 1] = v4.y;
    tile[lr + i * 16][lc + 2] = v4.z; tile[lr + i * 16][lc + 3] = v4.w;
  }
  __syncthreads();
  int nl = t >> 2;
  int cc = (t & 3) * 16;
  bf16_t* dst = fT + ((long)b * NN + n0 + nl) * NC + c0 + cc;
  union { bf16_t h[8]; uint4 u; } p0, p1;
#pragma unroll
  for (int j = 0; j < 8; j++) p0.h[j] = (bf16_t)tile[cc + j][nl];
#pragma unroll
  for (int j = 0; j < 8; j++) p1.h[j] = (bf16_t)tile[cc + 8 + j][nl];
  *(uint4*)dst = p0.u;
  *(uint4*)(dst + 8) = p1.u;
}

// ---------------- Kernel 2: projection GEMM [768,256]x[256,32768] ------------
// XCD-aware: the 6 blocks sharing one fT tile differ by 256 (same XCD -> L2 hit)
// outputs (fp8 e4m3), PAIRED frag-major for 16x16x32 mfma (16B/lane slots):
//   q tiles Kd[b][nt]: byte ((j>>1)*2+h)*1024 + l*16 + (j&1)*8 + e
//       = q[n=16h+(l&15)][c=j*32+((l>>4)&3)*8+e]
//   v tiles vD[b][nt]: byte (ct>>1)*1024 + l*16 + (ct&1)*8 + e
//       = v[c=ct*16+(l&15)][n=16(e>>2)+4((l>>4)&3)+(e&3)]
//   k as [B][N][C]
__global__ __launch_bounds__(256) void kproj(const bf16_t* __restrict__ Wc, const float* __restrict__ bc,
                                             const bf16_t* __restrict__ fT,
                                             unsigned char* __restrict__ qT8, unsigned char* __restrict__ kT8,
                                             unsigned char* __restrict__ vO8) {
  __shared__ bf16_t ft[128 * 256];  // XOR-swizzled rows, 64KB
  int bid = blockIdx.x;
  int mt = bid >> 8;          // 0..5
  int nb = bid & 255;         // 0..255: sharers of one fT tile are +256 apart
  int d0 = mt * 128;
  int gc0 = nb * 128;
  int b = gc0 >> 12;
  int n0 = gc0 & 4095;
  int t = threadIdx.x, lane = t & 63, w = t >> 6;
  int lm = lane & 31, g = lane >> 5;
  const bf16_t* ftb = fT + ((long)b * NN + n0) * NC;
#pragma unroll
  for (int i2 = 0; i2 < 16; i2++) {
    int call = w * 16 + i2;
    int p = call * 1024 + lane * 16;
    int n = p >> 9, cb = p & 511;
    int scb = cb ^ ((n & 7) << 4);
    gload_lds16(ftb + (long)n * NC + (scb >> 1), (char*)ft + call * 1024);
  }
  __syncthreads();

  f32x16 acc00 = fzero(), acc01 = fzero(), acc10 = fzero(), acc11 = fzero();
  int dbase = d0 + (w >> 1) * 64;
  int nbase = (w & 1) * 64;
  const bf16_t* wr = Wc + (long)dbase * NC;
#pragma unroll
  for (int j = 0; j < 16; j++) {
    int cc = j * 16 + g * 8;
    bf16x8 a0 = *(const bf16x8*)(wr + (long)lm * NC + cc);
    bf16x8 a1 = *(const bf16x8*)(wr + (long)(lm + 32) * NC + cc);
    int row0 = nbase + lm;
    bf16x8 b0 = *(const bf16x8*)((char*)ft + row0 * 512 + ((cc * 2) ^ ((row0 & 7) << 4)));
    int row1 = row0 + 32;
    bf16x8 b1 = *(const bf16x8*)((char*)ft + row1 * 512 + ((cc * 2) ^ ((row1 & 7) << 4)));
    acc00 = mfma32(a0, b0, acc00);
    acc01 = mfma32(a0, b1, acc01);
    acc10 = mfma32(a1, b0, acc10);
    acc11 = mfma32(a1, b1, acc11);
  }

  auto epi = [&](f32x16 a, int dt, int nt2) {
    int db = dbase + dt * 32;
    int colg = n0 + nbase + nt2 * 32 + lm;
    long tb = ((long)b * 128 + (colg >> 5)) * 8192;
    int n5 = colg & 31;
    if (mt >= 4) {        // v rows -> paired frag-major fp8 vD (byte stores)
      int q5 = (n5 >> 2) & 3;
      int e5 = ((n5 >> 4) << 2) + (n5 & 3);
      int ct0 = (db - 512) >> 4;
#pragma unroll
      for (int r = 0; r < 16; r++) {
        int d = db + (r & 3) + 8 * (r >> 2) + 4 * g;
        int ct = ct0 + (r >> 3);
        int kq = (r & 3) + 8 * ((r >> 2) & 1) + 4 * g;
        unsigned int f8 = __builtin_amdgcn_cvt_pk_fp8_f32(a[r] + bc[d], 0.f, 0, false);
        vO8[tb + (ct >> 1) * 1024 + (q5 * 16 + kq) * 16 + (ct & 1) * 8 + e5] = (unsigned char)f8;
      }
    } else if (mt < 2) {  // q rows -> paired frag-major fp8 Kd (u32 stores)
      int h = (n5 >> 4) & 1;
      int nr = n5 & 15;
      int j = db >> 5;
      long ob = tb + ((j >> 1) * 2 + h) * 1024 + (j & 1) * 8;
#pragma unroll
      for (int t4 = 0; t4 < 4; t4++) {
        int cb = db + 8 * t4 + 4 * g;
        unsigned int pk = __builtin_amdgcn_cvt_pk_fp8_f32(a[4 * t4 + 0] + bc[cb + 0],
                                                          a[4 * t4 + 1] + bc[cb + 1], 0, false);
        pk = __builtin_amdgcn_cvt_pk_fp8_f32(a[4 * t4 + 2] + bc[cb + 2],
                                             a[4 * t4 + 3] + bc[cb + 3], pk, true);
        *(unsigned int*)(qT8 + ob + (t4 * 16 + nr) * 16 + 4 * g) = pk;
      }
    } else {              // k rows -> [B][N][C] fp8 (pair ushort stores)
      unsigned char* dst = kT8 + ((long)b * NN + colg) * 256 - 256;
#pragma unroll
      for (int r2 = 0; r2 < 8; r2++) {
        int r = r2 * 2;
        int d = db + (r & 3) + 8 * (r >> 2) + 4 * g;
        unsigned int pk = __builtin_amdgcn_cvt_pk_fp8_f32(a[r] + bc[d], a[r + 1] + bc[d + 1], 0, false);
        *(unsigned short*)(dst + d) = (unsigned short)pk;
      }
    }
  };
  epi(acc00, 0, 0); epi(acc01, 0, 1); epi(acc10, 1, 0); epi(acc11, 1, 1);
}

// ---------------- Kernel 3: fp8 flash attention, 16x16 frags, 8 waves --------
// Exact R13 structure (dbuf, one barrier/iter, nsplit=2, 4 waves/SIMD).
// Partials written as [b][c/2][m] uint (bf16 c-pair) for coalesced combine.
__global__ __launch_bounds__(512, 4) void kattn(const unsigned char* __restrict__ qT8,
                                                const unsigned char* __restrict__ kT8,
                                                const unsigned char* __restrict__ vO8,
                                                char* __restrict__ R0, char* __restrict__ R1, int iters) {
  __shared__ unsigned char Kt[2][8192];   // paired frag-major fp8
  __shared__ unsigned char Vt[2][8192];
  int bid = blockIdx.x;
  int b = bid & 7;
  int mtile = (bid >> 3) & 31;
  int split = bid >> 8;
  int nt0 = split * iters, ntE = nt0 + iters;
  int t = threadIdx.x, lane = t & 63, w = t >> 6;   // 8 waves
  int l4 = lane & 15, q = (lane >> 4) & 3;
  int mw = mtile * 128 + w * 16;
  const unsigned char* qb = qT8 + (long)b * 1048576;    // 128 tiles x 8192 B
  const unsigned char* vtb = vO8 + (long)b * 1048576;

  // B-frags of the flash-query (k-projection), col m = l4, k = q*8+e
  uint2 qf[8];
  const unsigned char* kb = kT8 + ((long)b * NN + mw + l4) * 256 + q * 8;
#pragma unroll
  for (int j = 0; j < 8; j++) qf[j] = *(const uint2*)(kb + j * 32);

  f32x4 acc[16];
#pragma unroll
  for (int ct = 0; ct < 16; ct++) acc[ct] = f32x4{0.f, 0.f, 0.f, 0.f};
  float lsum = 0.f;

  auto stageK = [&](int nt, int bufi) {
    gload_lds16(qb + (long)nt * 8192 + w * 1024 + lane * 16, &Kt[bufi][w * 1024]);
  };
  auto stageV = [&](int nt, int bufi) {
    gload_lds16(vtb + (long)nt * 8192 + w * 1024 + lane * 16, &Vt[bufi][w * 1024]);
  };

  stageK(nt0, 0);
  stageV(nt0, 0);
  __syncthreads();

  int buf = 0;
  for (int nt = nt0; nt < ntE; nt++) {
    bool more = nt + 1 < ntE;
    if (more) { stageK(nt + 1, buf ^ 1); stageV(nt + 1, buf ^ 1); }
    // ---- QK^T (swapped): paired b128 frag reads, 4 mfma per j2 ----
    __builtin_amdgcn_s_setprio(1);
    const unsigned char* kbase = &Kt[buf][0] + lane * 16;
    f32x4 s0 = f32x4{0.f, 0.f, 0.f, 0.f}, s1 = f32x4{0.f, 0.f, 0.f, 0.f};
#pragma unroll
    for (int j2 = 0; j2 < 4; j2++) {
      uint4 h0 = *(const uint4*)(kbase + (j2 * 2) * 1024);
      s0 = mfma16(make_uint2(h0.x, h0.y), qf[2 * j2], s0);
      s0 = mfma16(make_uint2(h0.z, h0.w), qf[2 * j2 + 1], s0);
      uint4 h1 = *(const uint4*)(kbase + (j2 * 2 + 1) * 1024);
      s1 = mfma16(make_uint2(h1.x, h1.y), qf[2 * j2], s1);
      s1 = mfma16(make_uint2(h1.z, h1.w), qf[2 * j2 + 1], s1);
    }
    __builtin_amdgcn_s_setprio(0);
    // ---- softmax (exp2 domain, no shift); lane holds 8 of 32 n's ----
    float e[8];
#pragma unroll
    for (int r = 0; r < 4; r++) {
      e[r] = __builtin_amdgcn_exp2f(s0[r] * QSCALE);
      e[4 + r] = __builtin_amdgcn_exp2f(s1[r] * QSCALE);
    }
    lsum += ((e[0] + e[1]) + (e[2] + e[3])) + ((e[4] + e[5]) + (e[6] + e[7]));
    uint2 pf;
    pf.x = __builtin_amdgcn_cvt_pk_fp8_f32(e[0], e[1], 0, false);
    pf.x = __builtin_amdgcn_cvt_pk_fp8_f32(e[2], e[3], pf.x, true);
    pf.y = __builtin_amdgcn_cvt_pk_fp8_f32(e[4], e[5], 0, false);
    pf.y = __builtin_amdgcn_cvt_pk_fp8_f32(e[6], e[7], pf.y, true);
    // ---- PV: paired b128 frag reads, 2 mfma per ct2 ----
    __builtin_amdgcn_s_setprio(1);
    const unsigned char* vbase = &Vt[buf][0] + lane * 16;
#pragma unroll
    for (int ct2 = 0; ct2 < 8; ct2++) {
      uint4 vv = *(const uint4*)(vbase + ct2 * 1024);
      acc[2 * ct2] = mfma16(make_uint2(vv.x, vv.y), pf, acc[2 * ct2]);
      acc[2 * ct2 + 1] = mfma16(make_uint2(vv.z, vv.w), pf, acc[2 * ct2 + 1]);
    }
    __builtin_amdgcn_s_setprio(0);
    __syncthreads();
    buf ^= 1;
  }
  // ---- epilogue: partials as [b][c/2][m] uint; L as [b][m] f32 ----
  float ltot = lsum + __shfl_xor(lsum, 16, 64);
  ltot += __shfl_xor(ltot, 32, 64);
  char* R = split ? R1 : R0;
  unsigned int* PP = (unsigned int*)R;
  float* MLf = (float*)(R + 16777216);
  if (lane < 16) MLf[b * 4096 + mw + lane] = ltot;
  long base = ((long)b * 128) * 4096 + mw + l4;
#pragma unroll
  for (int ct = 0; ct < 16; ct++) {
    int cp0 = ct * 8 + q * 2;   // c = ct*16 + q*4 + r ; pair (r=0,1) and (r=2,3)
    PP[base + (long)cp0 * 4096] = packbf2(acc[ct][0], acc[ct][1]);
    PP[base + (long)(cp0 + 1) * 4096] = packbf2(acc[ct][2], acc[ct][3]);
  }
}

// ---------------- Kernel 4: combine splits, normalize, gamma*o + x -----------
// 2 m's per thread: uint2 partials, f32x2 L/x loads, nontemporal f32x2 stores.
__global__ __launch_bounds__(256) void kcombine(const char* __restrict__ R0, const char* __restrict__ R1,
                                                int nsplit, const float* __restrict__ x,
                                                const float* __restrict__ gma, float* __restrict__ out) {
  int tid = blockIdx.x * 256 + threadIdx.x;   // 2.097M threads, 4 outputs each
  int pi = tid * 2;                            // partial word index [b][cp][m]
  int b = pi >> 19;
  int cp = (pi >> 12) & 127;
  int m = pi & 4095;                           // even
  uint2 p0 = ((const uint2*)R0)[tid];
  f32x2 Lv = *(const f32x2*)((const float*)(R0 + 16777216) + b * 4096 + m);
  float ox0 = __uint_as_float(p0.x << 16);
  float oy0 = __uint_as_float(p0.x & 0xffff0000u);
  float ox1 = __uint_as_float(p0.y << 16);
  float oy1 = __uint_as_float(p0.y & 0xffff0000u);
  if (nsplit == 2) {      // no shift: splits combine by plain addition
    uint2 p1 = ((const uint2*)R1)[tid];
    f32x2 Lv1 = *(const f32x2*)((const float*)(R1 + 16777216) + b * 4096 + m);
    ox0 += __uint_as_float(p1.x << 16);
    oy0 += __uint_as_float(p1.x & 0xffff0000u);
    ox1 += __uint_as_float(p1.y << 16);
    oy1 += __uint_as_float(p1.y & 0xffff0000u);
    Lv.x += Lv1.x; Lv.y += Lv1.y;
  }
  float gm = gma[0];
  float sc0 = gm / Lv.x, sc1 = gm / Lv.y;
  long o0 = ((long)(b * NC + 2 * cp)) * NN + m;
  f32x2 xa = *(const f32x2*)(x + o0);
  f32x2 xb = *(const f32x2*)(x + o0 + NN);
  f32x2 ra; ra.x = ox0 * sc0 + xa.x; ra.y = ox1 * sc1 + xa.y;
  f32x2 rb; rb.x = oy0 * sc0 + xb.x; rb.y = oy1 * sc1 + xb.y;
  __builtin_nontemporal_store(ra, (f32x2*)(out + o0));
  __builtin_nontemporal_store(rb, (f32x2*)(out + o0 + NN));
}

extern "C" void kernel_launch(void* const* d_in, const int* in_sizes, int n_in,
                              void* d_out, int out_size, void* d_ws, size_t ws_size,
                              hipStream_t stream) {
  const float* x   = (const float*)d_in[0];
  const float* Wq  = (const float*)d_in[1];
  const float* bq  = (const float*)d_in[2];
  const float* Wk  = (const float*)d_in[3];
  const float* bk  = (const float*)d_in[4];
  const float* Wv  = (const float*)d_in[5];
  const float* bv  = (const float*)d_in[6];
  const float* gma = (const float*)d_in[7];
  float* out = (float*)d_out;
  char* ws = (char*)d_ws;
  // layout (bytes): qT8 8.39M | kT8 8.39M | vO8 8.39M | fT 16.78M | Wc | bc | R1
  unsigned char* qT8 = (unsigned char*)(ws);
  unsigned char* kT8 = (unsigned char*)(ws + 8388608);
  unsigned char* vO8 = (unsigned char*)(ws + 16777216);
  bf16_t* fT = (bf16_t*)(ws + 25165824);
  bf16_t* Wc = (bf16_t*)(ws + 41943040);
  float*  bc = (float*)(ws + 42336256);
  const size_t RSZ = 16908288;   // 16.78M partials + 131KB L
  char* R0 = ws + 25165824;      // reuses fT + Wc/bc (dead after kproj)
  char* R1 = ws + 42340352;
  size_t need2 = 42340352 + RSZ;
  int nsplit = (ws_size >= need2) ? 2 : 1;

  ktranspose<<<2048, 256, 0, stream>>>(x, fT, Wq, bq, Wk, bk, Wv, bv, Wc, bc);
  kproj<<<1536, 256, 0, stream>>>(Wc, bc, fT, qT8, kT8, vO8);
  kattn<<<256 * nsplit, 512, 0, stream>>>(qT8, kT8, vO8, R0, R1, 128 / nsplit);
  kcombine<<<8192, 256, 0, stream>>>(R0, R1, nsplit, x, gma, out);
}